// Round 1
// baseline (1245.591 us; speedup 1.0000x reference)
//
#include <hip/hip_runtime.h>

#define N_NODES 50000
#define KNB 32
#define DIM 128
#define HDIM 32

typedef _Float16 f16x8 __attribute__((ext_vector_type(8)));
typedef float f32x16 __attribute__((ext_vector_type(16)));

__device__ __forceinline__ float fast_tanh(float x) {
  float xc = fminf(fmaxf(x, -15.f), 15.f);
  float e = __expf(2.f * xc);
  return (e - 1.f) / (e + 1.f);
}

// Kernel 1: one wave per node. Fused att1 (MFMA) -> tanh -> scores -> softmax -> agg.
// Writes agg (fp32) into out[n*256 + 128 .. 255].
__global__ __launch_bounds__(256) void k_att(
    const float* __restrict__ node_feats, const float* __restrict__ neib_feats,
    const float* __restrict__ W_att1, const float* __restrict__ W_att2,
    float* __restrict__ out) {
  __shared__ float w2p[HDIM * 33];   // W_att2 padded [32][33] -> conflict-free both access patterns
  __shared__ float s_tn[4][HDIM];
  __shared__ float s_na[4][HDIM];
  __shared__ float s_sc[4][KNB];

  const int tid = threadIdx.x;
  const int wv = tid >> 6;   // wave in block
  const int l = tid & 63;    // lane
  const int lg = l & 31;     // col-lane (g / k / n index)
  const int hf = l >> 5;     // half of wave

  // stage W_att2 padded
  for (int i = tid; i < HDIM * HDIM; i += 256)
    w2p[(i >> 5) * 33 + (i & 31)] = W_att2[i];

  // preload W_att1 as MFMA B-fragments: B[k=d][n=g], lane l holds k = s*16 + hf*8 + j, n = lg
  f16x8 b1[8];
#pragma unroll
  for (int s = 0; s < 8; ++s) {
#pragma unroll
    for (int j = 0; j < 8; ++j) {
      int d = s * 16 + hf * 8 + j;
      b1[s][j] = (_Float16)W_att1[d * HDIM + lg];
    }
  }
  __syncthreads();

  const int waveG = blockIdx.x * 4 + wv;
  const int nW = gridDim.x * 4;
  const int iters = (N_NODES + nW - 1) / nW;

  for (int it = 0; it < iters; ++it) {
    const int n = waveG + it * nW;
    const bool active = n < N_NODES;
    const int nn = active ? n : N_NODES - 1;
    const float* nb = neib_feats + (size_t)nn * (KNB * DIM);
    const float* nd = node_feats + (size_t)nn * DIM;

    // att1 for the 32 neighbors (acc) and for the node row broadcast to all 32 rows (acc2)
    f32x16 acc = {0.f, 0.f, 0.f, 0.f, 0.f, 0.f, 0.f, 0.f,
                  0.f, 0.f, 0.f, 0.f, 0.f, 0.f, 0.f, 0.f};
    f32x16 acc2 = {0.f, 0.f, 0.f, 0.f, 0.f, 0.f, 0.f, 0.f,
                   0.f, 0.f, 0.f, 0.f, 0.f, 0.f, 0.f, 0.f};
#pragma unroll
    for (int s = 0; s < 8; ++s) {
      // A[m=lg][k = s*16 + hf*8 + j]
      const float* srcA = nb + lg * DIM + s * 16 + hf * 8;
      const float* srcN = nd + s * 16 + hf * 8;
      f16x8 a, an;
#pragma unroll
      for (int j = 0; j < 8; ++j) {
        a[j] = (_Float16)srcA[j];
        an[j] = (_Float16)srcN[j];   // uniform across 32-group -> broadcast load
      }
      acc = __builtin_amdgcn_mfma_f32_32x32x16_f16(a, b1[s], acc, 0, 0, 0);
      acc2 = __builtin_amdgcn_mfma_f32_32x32x16_f16(an, b1[s], acc2, 0, 0, 0);
    }

    // tanh. C layout: col = lg, row = (r&3) + 8*(r>>2) + 4*hf
    float T[16];
#pragma unroll
    for (int r = 0; r < 16; ++r) T[r] = fast_tanh(acc[r]);

    // node path: acc2 reg0 = node_att1[g=lg] (identical rows), tanh -> LDS
    float tn = fast_tanh(acc2[0]);
    if (l < 32) s_tn[wv][l] = tn;
    __syncthreads();  // barrier 1

    // node_att2[h=lg] = sum_g tanh_node[g] * W2[g][h]
    float na = 0.f;
#pragma unroll
    for (int g = 0; g < HDIM; ++g) na = fmaf(s_tn[wv][g], w2p[g * 33 + lg], na);
    if (l < 32) s_na[wv][l] = na;
    __syncthreads();  // barrier 2

    // v[g=lg] = sum_h W2[g][h] * node_att2[h]
    float v = 0.f;
#pragma unroll
    for (int h = 0; h < HDIM; ++h) v = fmaf(w2p[lg * 33 + h], s_na[wv][h], v);

    // scores[k_row] = sum_g T[row][g] * v[g] ; butterfly over the 32-lane group
#pragma unroll
    for (int r = 0; r < 16; ++r) {
      float p = T[r] * v;
#pragma unroll
      for (int off = 1; off <= 16; off <<= 1) p += __shfl_xor(p, off);
      if (lg == 0) s_sc[wv][(r & 3) + 8 * (r >> 2) + 4 * hf] = p;
    }
    __syncthreads();  // barrier 3

    // softmax over k (lane lg holds score k=lg; halves duplicate)
    float sc = s_sc[wv][lg];
    float mx = sc;
#pragma unroll
    for (int off = 16; off; off >>= 1) mx = fmaxf(mx, __shfl_xor(mx, off));
    float e = __expf(sc - mx);
    float sum = e;
#pragma unroll
    for (int off = 16; off; off >>= 1) sum += __shfl_xor(sum, off);
    float w = e / sum;

    // agg[d] = sum_k w[k] * neib[k][d]; lane handles d = 2l, 2l+1 (coalesced, L1/L2-hot rows)
    float a0 = 0.f, a1 = 0.f;
#pragma unroll 8
    for (int k = 0; k < KNB; ++k) {
      float wk = __shfl(w, k, 32);
      float2 rv = *(const float2*)(nb + k * DIM + 2 * l);
      a0 = fmaf(wk, rv.x, a0);
      a1 = fmaf(wk, rv.y, a1);
    }
    if (active)
      *(float2*)(out + (size_t)n * 256 + 128 + 2 * l) = make_float2(a0, a1);
    // next iteration's first LDS write is preceded by barrier 1, which orders it
    // after this iteration's s_sc reads (all threads must pass it first)
  }
}

// Kernel 2: out[:,0:128] = relu(node_feats @ W_node); out[:,128:256] = relu(agg @ W_neib)
// agg read in place from out[:,128:256] (each wave reads only its own rows before storing).
__global__ __launch_bounds__(256) void k_out(
    const float* __restrict__ node_feats, const float* __restrict__ W_node,
    const float* __restrict__ W_neib, float* __restrict__ out) {
  const int tid = threadIdx.x;
  const int wv = tid >> 6;
  const int l = tid & 63;
  const int lg = l & 31;
  const int hf = l >> 5;
  const int half = blockIdx.y;  // 0: node half, 1: agg half

  const float* W = half ? W_neib : W_node;
  const int r0 = blockIdx.x * 128 + wv * 32;
  const int row = r0 + lg;
  const int rowc = row < N_NODES ? row : N_NODES - 1;

  const float* X = half ? (out + 128) : node_feats;
  const size_t pitch = half ? 256 : DIM;

  // A-fragments: A[m=lg][k = s*16 + hf*8 + j] for this wave's 32 rows
  f16x8 a[8];
#pragma unroll
  for (int s = 0; s < 8; ++s) {
    const float* src = X + (size_t)rowc * pitch + s * 16 + hf * 8;
#pragma unroll
    for (int j = 0; j < 8; ++j) a[s][j] = (_Float16)src[j];
  }

  for (int ct = 0; ct < 4; ++ct) {
    f32x16 acc = {0.f, 0.f, 0.f, 0.f, 0.f, 0.f, 0.f, 0.f,
                  0.f, 0.f, 0.f, 0.f, 0.f, 0.f, 0.f, 0.f};
#pragma unroll
    for (int s = 0; s < 8; ++s) {
      f16x8 b;
#pragma unroll
      for (int j = 0; j < 8; ++j) {
        int d = s * 16 + hf * 8 + j;
        b[j] = (_Float16)W[d * 128 + ct * 32 + lg];
      }
      acc = __builtin_amdgcn_mfma_f32_32x32x16_f16(a[s], b, acc, 0, 0, 0);
    }
#pragma unroll
    for (int r = 0; r < 16; ++r) {
      int orow = r0 + (r & 3) + 8 * (r >> 2) + 4 * hf;
      if (orow < N_NODES)
        out[(size_t)orow * 256 + half * 128 + ct * 32 + lg] = fmaxf(acc[r], 0.f);
    }
  }
}

extern "C" void kernel_launch(void* const* d_in, const int* in_sizes, int n_in,
                              void* d_out, int out_size, void* d_ws, size_t ws_size,
                              hipStream_t stream) {
  (void)in_sizes; (void)n_in; (void)d_ws; (void)ws_size; (void)out_size;
  const float* node_feats = (const float*)d_in[0];
  const float* neib_feats = (const float*)d_in[1];
  // d_in[2] node_ids, d_in[3] neib_ids: unused by the reference
  const float* W_att1 = (const float*)d_in[4];
  const float* W_att2 = (const float*)d_in[5];
  const float* W_node = (const float*)d_in[6];
  const float* W_neib = (const float*)d_in[7];
  float* out = (float*)d_out;

  k_att<<<dim3(768), dim3(256), 0, stream>>>(node_feats, neib_feats, W_att1, W_att2, out);
  k_out<<<dim3((N_NODES + 127) / 128, 2), dim3(256), 0, stream>>>(node_feats, W_node, W_neib, out);
}

// Round 2
// 1150.220 us; speedup vs baseline: 1.0829x; 1.0829x over previous
//
#include <hip/hip_runtime.h>

#define N_NODES 50000
#define KNB 32
#define DIM 128
#define HDIM 32

typedef _Float16 f16x8 __attribute__((ext_vector_type(8)));
typedef float f32x16 __attribute__((ext_vector_type(16)));

__device__ __forceinline__ float fast_tanh(float x) {
  float xc = fminf(fmaxf(x, -10.f), 10.f);
  float e = __expf(2.f * xc);
  return (e - 1.f) * __builtin_amdgcn_rcpf(e + 1.f);
}

__device__ __forceinline__ f32x16 zero16() {
  f32x16 z;
#pragma unroll
  for (int i = 0; i < 16; ++i) z[i] = 0.f;
  return z;
}

// Kernel A (one-shot): per wave handles 32 node rows.
//   v_ws[n,g] = (tanh(node@W1) @ M)[n,g],  M = W2 @ W2^T   (scores = T_neib . v)
//   out[:,0:128] = relu(node @ W_node)
__global__ __launch_bounds__(256) void k_node(
    const float* __restrict__ node_feats, const float* __restrict__ W_att1,
    const float* __restrict__ W_att2, const float* __restrict__ W_node,
    float* __restrict__ out, float* __restrict__ v_ws) {
  __shared__ float w2s[HDIM * HDIM];
  __shared__ float Ms[HDIM * 33];     // padded
  __shared__ float T2[4][HDIM * 36];  // per-wave transpose buffer, pad 36 (16B-aligned rows)

  const int tid = threadIdx.x;
  const int wv = tid >> 6, l = tid & 63, lg = l & 31, hf = l >> 5;

  for (int i = tid; i < HDIM * HDIM; i += 256) w2s[i] = W_att2[i];
  __syncthreads();
  for (int e = tid; e < HDIM * HDIM; e += 256) {
    int g = e >> 5, gp = e & 31;
    float s = 0.f;
#pragma unroll
    for (int h = 0; h < HDIM; ++h) s = fmaf(w2s[g * 32 + h], w2s[gp * 32 + h], s);
    Ms[g * 33 + gp] = s;
  }
  __syncthreads();

  const int r0 = blockIdx.x * 128 + wv * 32;
  const int row = r0 + lg;
  const int rowc = row < N_NODES ? row : N_NODES - 1;

  // A-fragments of 32 node rows: A[m=lg][k=s*16+hf*8+j]
  f16x8 af[8];
#pragma unroll
  for (int s = 0; s < 8; ++s) {
    const float* src = node_feats + (size_t)rowc * DIM + s * 16 + hf * 8;
#pragma unroll
    for (int j = 0; j < 8; ++j) af[s][j] = (_Float16)src[j];
  }

  // node @ W_att1
  f32x16 acc1 = zero16();
#pragma unroll
  for (int s = 0; s < 8; ++s) {
    f16x8 b;
#pragma unroll
    for (int j = 0; j < 8; ++j)
      b[j] = (_Float16)W_att1[(s * 16 + hf * 8 + j) * HDIM + lg];
    acc1 = __builtin_amdgcn_mfma_f32_32x32x16_f16(af[s], b, acc1, 0, 0, 0);
  }
  // tanh, transpose C-layout -> row-major via LDS
#pragma unroll
  for (int r = 0; r < 16; ++r)
    T2[wv][((r & 3) + 8 * (r >> 2) + 4 * hf) * 36 + lg] = fast_tanh(acc1[r]);
  __syncthreads();

  // v = T @ M  (K=32 -> 2 slices)
  f32x16 accv = zero16();
#pragma unroll
  for (int s = 0; s < 2; ++s) {
    f16x8 a2, mb;
#pragma unroll
    for (int j = 0; j < 8; ++j) {
      a2[j] = (_Float16)T2[wv][lg * 36 + s * 16 + hf * 8 + j];
      mb[j] = (_Float16)Ms[(s * 16 + hf * 8 + j) * 33 + lg];
    }
    accv = __builtin_amdgcn_mfma_f32_32x32x16_f16(a2, mb, accv, 0, 0, 0);
  }
#pragma unroll
  for (int r = 0; r < 16; ++r) {
    int orow = r0 + (r & 3) + 8 * (r >> 2) + 4 * hf;
    if (orow < N_NODES) v_ws[orow * HDIM + lg] = accv[r];
  }

  // out[:,0:128] = relu(node @ W_node)
  for (int ct = 0; ct < 4; ++ct) {
    f32x16 acc = zero16();
#pragma unroll
    for (int s = 0; s < 8; ++s) {
      f16x8 b;
#pragma unroll
      for (int j = 0; j < 8; ++j)
        b[j] = (_Float16)W_node[(s * 16 + hf * 8 + j) * 128 + ct * 32 + lg];
      acc = __builtin_amdgcn_mfma_f32_32x32x16_f16(af[s], b, acc, 0, 0, 0);
    }
#pragma unroll
    for (int r = 0; r < 16; ++r) {
      int orow = r0 + (r & 3) + 8 * (r >> 2) + 4 * hf;
      if (orow < N_NODES) out[(size_t)orow * 256 + ct * 32 + lg] = fmaxf(acc[r], 0.f);
    }
  }
}

// Kernel B (hot): one wave per node, persistent grid-stride. No LDS, no barriers.
//   C = W1^T @ neib^T via MFMA: tile regs are the B-operand (same load pattern as an
//   A-frag of neib). C[m=g][n=k] -> scores land with k = lane: softmax in-lane.
//   agg re-reads the (cache-hot) tile coalesced; writes out[:,128:256].
__global__ __launch_bounds__(256, 3) void k_att(
    const float* __restrict__ neib_feats, const float* __restrict__ W_att1,
    const float* __restrict__ v_ws, float* __restrict__ out) {
  const int tid = threadIdx.x;
  const int wv = tid >> 6, l = tid & 63, lg = l & 31, hf = l >> 5;

  // A-frags of W1^T: A[m=g=lg][k=d=s*16+hf*8+j] = W1[d, lg]
  f16x8 w1t[8];
#pragma unroll
  for (int s = 0; s < 8; ++s) {
#pragma unroll
    for (int j = 0; j < 8; ++j)
      w1t[s][j] = (_Float16)W_att1[(s * 16 + hf * 8 + j) * HDIM + lg];
  }

  const int waveG = blockIdx.x * 4 + wv;
  const int nW = gridDim.x * 4;

  for (int n = waveG; n < N_NODES; n += nW) {
    const float* nb = neib_feats + (size_t)n * (KNB * DIM);

    // B-frags of neib^T: B[k=d][n=neighbor=lg] = neib[lg, d]
    f32x16 acc = zero16();
#pragma unroll
    for (int s = 0; s < 8; ++s) {
      const float* src = nb + lg * DIM + s * 16 + hf * 8;
      f16x8 b;
#pragma unroll
      for (int j = 0; j < 8; ++j) b[j] = (_Float16)src[j];
      acc = __builtin_amdgcn_mfma_f32_32x32x16_f16(w1t[s], b, acc, 0, 0, 0);
    }

    // C[m=g=(r&3)+8*(r>>2)+4*hf][n=k=lg]; score_k = sum_g tanh(C[g,k]) * v[n,g]
    const float* vn = v_ws + n * HDIM;
    float p = 0.f;
#pragma unroll
    for (int r = 0; r < 16; ++r) {
      float t = fast_tanh(acc[r]);
      p = fmaf(t, vn[(r & 3) + 8 * (r >> 2) + 4 * hf], p);  // lane-uniform per half -> broadcast load
    }
    p += __shfl_xor(p, 32, 64);  // combine the two halves' g-partitions

    // softmax over k (lane lg holds score k=lg, duplicated across halves)
    float mx = p;
#pragma unroll
    for (int off = 16; off; off >>= 1) mx = fmaxf(mx, __shfl_xor(mx, off, 32));
    float e = __expf(p - mx);
    float sum = e;
#pragma unroll
    for (int off = 16; off; off >>= 1) sum += __shfl_xor(sum, off, 32);
    float w = e * __builtin_amdgcn_rcpf(sum);

    // agg[d] = sum_k w[k]*neib[k,d]; lane covers d=2l,2l+1 (coalesced, cache-hot rows)
    float a0 = 0.f, a1 = 0.f;
#pragma unroll 8
    for (int k = 0; k < KNB; ++k) {
      float wk = __shfl(w, k, 32);
      float2 rv = *(const float2*)(nb + k * DIM + 2 * l);
      a0 = fmaf(wk, rv.x, a0);
      a1 = fmaf(wk, rv.y, a1);
    }
    *(float2*)(out + (size_t)n * 256 + 128 + 2 * l) = make_float2(a0, a1);
  }
}

// Kernel C: out[:,128:256] = relu(agg @ W_neib), agg read in place (each wave
// loads all its rows into regs before any store).
__global__ __launch_bounds__(256) void k_neib(
    const float* __restrict__ W_neib, float* __restrict__ out) {
  const int tid = threadIdx.x;
  const int wv = tid >> 6, l = tid & 63, lg = l & 31, hf = l >> 5;
  const int r0 = blockIdx.x * 128 + wv * 32;
  const int row = r0 + lg;
  const int rowc = row < N_NODES ? row : N_NODES - 1;

  f16x8 af[8];
#pragma unroll
  for (int s = 0; s < 8; ++s) {
    const float* src = out + (size_t)rowc * 256 + 128 + s * 16 + hf * 8;
#pragma unroll
    for (int j = 0; j < 8; ++j) af[s][j] = (_Float16)src[j];
  }

  for (int ct = 0; ct < 4; ++ct) {
    f32x16 acc = zero16();
#pragma unroll
    for (int s = 0; s < 8; ++s) {
      f16x8 b;
#pragma unroll
      for (int j = 0; j < 8; ++j)
        b[j] = (_Float16)W_neib[(s * 16 + hf * 8 + j) * 128 + ct * 32 + lg];
      acc = __builtin_amdgcn_mfma_f32_32x32x16_f16(af[s], b, acc, 0, 0, 0);
    }
#pragma unroll
    for (int r = 0; r < 16; ++r) {
      int orow = r0 + (r & 3) + 8 * (r >> 2) + 4 * hf;
      if (orow < N_NODES) out[(size_t)orow * 256 + 128 + ct * 32 + lg] = fmaxf(acc[r], 0.f);
    }
  }
}

extern "C" void kernel_launch(void* const* d_in, const int* in_sizes, int n_in,
                              void* d_out, int out_size, void* d_ws, size_t ws_size,
                              hipStream_t stream) {
  (void)in_sizes; (void)n_in; (void)ws_size; (void)out_size;
  const float* node_feats = (const float*)d_in[0];
  const float* neib_feats = (const float*)d_in[1];
  const float* W_att1 = (const float*)d_in[4];
  const float* W_att2 = (const float*)d_in[5];
  const float* W_node = (const float*)d_in[6];
  const float* W_neib = (const float*)d_in[7];
  float* out = (float*)d_out;
  float* v_ws = (float*)d_ws;  // N_NODES * 32 floats = 6.4 MB

  const int nblk = (N_NODES + 127) / 128;  // 391
  k_node<<<dim3(nblk), dim3(256), 0, stream>>>(node_feats, W_att1, W_att2, W_node, out, v_ws);
  k_att<<<dim3(1024), dim3(256), 0, stream>>>(neib_feats, W_att1, v_ws, out);
  k_neib<<<dim3(nblk), dim3(256), 0, stream>>>(W_neib, out);
}

// Round 3
// 1103.544 us; speedup vs baseline: 1.1287x; 1.0423x over previous
//
#include <hip/hip_runtime.h>

#define N_NODES 50000
#define KNB 32
#define DIM 128
#define HDIM 32
#define PITCH 132   // floats; 16B-aligned rows, frag reads 4-way (1.58x), agg reads 2-way (free)

typedef _Float16 f16x8 __attribute__((ext_vector_type(8)));
typedef float f32x16 __attribute__((ext_vector_type(16)));
typedef float f32x4 __attribute__((ext_vector_type(4)));

__device__ __forceinline__ float fast_tanh(float x) {
  float xc = fminf(fmaxf(x, -10.f), 10.f);
  float e = __expf(2.f * xc);
  return (e - 1.f) * __builtin_amdgcn_rcpf(e + 1.f);
}

__device__ __forceinline__ f32x16 zero16() {
  f32x16 z;
#pragma unroll
  for (int i = 0; i < 16; ++i) z[i] = 0.f;
  return z;
}

// Kernel A (one-shot): per wave handles 32 node rows.
//   v_ws[n,g] = (tanh(node@W1) @ M)[n,g],  M = W2 @ W2^T   (scores = T_neib . v)
//   out[:,0:128] = relu(node @ W_node)
__global__ __launch_bounds__(256) void k_node(
    const float* __restrict__ node_feats, const float* __restrict__ W_att1,
    const float* __restrict__ W_att2, const float* __restrict__ W_node,
    float* __restrict__ out, float* __restrict__ v_ws) {
  __shared__ float w2s[HDIM * HDIM];
  __shared__ float Ms[HDIM * 33];
  __shared__ float T2[4][HDIM * 36];

  const int tid = threadIdx.x;
  const int wv = tid >> 6, l = tid & 63, lg = l & 31, hf = l >> 5;

  for (int i = tid; i < HDIM * HDIM; i += 256) w2s[i] = W_att2[i];
  __syncthreads();
  for (int e = tid; e < HDIM * HDIM; e += 256) {
    int g = e >> 5, gp = e & 31;
    float s = 0.f;
#pragma unroll
    for (int h = 0; h < HDIM; ++h) s = fmaf(w2s[g * 32 + h], w2s[gp * 32 + h], s);
    Ms[g * 33 + gp] = s;
  }
  __syncthreads();

  const int r0 = blockIdx.x * 128 + wv * 32;
  const int row = r0 + lg;
  const int rowc = row < N_NODES ? row : N_NODES - 1;

  f16x8 af[8];
#pragma unroll
  for (int s = 0; s < 8; ++s) {
    const float* src = node_feats + (size_t)rowc * DIM + s * 16 + hf * 8;
#pragma unroll
    for (int j = 0; j < 8; ++j) af[s][j] = (_Float16)src[j];
  }

  f32x16 acc1 = zero16();
#pragma unroll
  for (int s = 0; s < 8; ++s) {
    f16x8 b;
#pragma unroll
    for (int j = 0; j < 8; ++j)
      b[j] = (_Float16)W_att1[(s * 16 + hf * 8 + j) * HDIM + lg];
    acc1 = __builtin_amdgcn_mfma_f32_32x32x16_f16(af[s], b, acc1, 0, 0, 0);
  }
#pragma unroll
  for (int r = 0; r < 16; ++r)
    T2[wv][((r & 3) + 8 * (r >> 2) + 4 * hf) * 36 + lg] = fast_tanh(acc1[r]);
  __syncthreads();

  f32x16 accv = zero16();
#pragma unroll
  for (int s = 0; s < 2; ++s) {
    f16x8 a2, mb;
#pragma unroll
    for (int j = 0; j < 8; ++j) {
      a2[j] = (_Float16)T2[wv][lg * 36 + s * 16 + hf * 8 + j];
      mb[j] = (_Float16)Ms[(s * 16 + hf * 8 + j) * 33 + lg];
    }
    accv = __builtin_amdgcn_mfma_f32_32x32x16_f16(a2, mb, accv, 0, 0, 0);
  }
#pragma unroll
  for (int r = 0; r < 16; ++r) {
    int orow = r0 + (r & 3) + 8 * (r >> 2) + 4 * hf;
    if (orow < N_NODES) v_ws[orow * HDIM + lg] = accv[r];
  }

  for (int ct = 0; ct < 4; ++ct) {
    f32x16 acc = zero16();
#pragma unroll
    for (int s = 0; s < 8; ++s) {
      f16x8 b;
#pragma unroll
      for (int j = 0; j < 8; ++j)
        b[j] = (_Float16)W_node[(s * 16 + hf * 8 + j) * 128 + ct * 32 + lg];
      acc = __builtin_amdgcn_mfma_f32_32x32x16_f16(af[s], b, acc, 0, 0, 0);
    }
#pragma unroll
    for (int r = 0; r < 16; ++r) {
      int orow = r0 + (r & 3) + 8 * (r >> 2) + 4 * hf;
      if (orow < N_NODES) out[(size_t)orow * 256 + ct * 32 + lg] = fmaxf(acc[r], 0.f);
    }
  }
}

// Kernel B (hot): one wave per node, persistent. Stage the 16KB tile into LDS ONCE
// (coalesced dwordx4), consume it twice from LDS (MFMA frags + agg). No barriers:
// LDS region is wave-private.
__global__ __launch_bounds__(256) void k_att(
    const float* __restrict__ neib_feats, const float* __restrict__ W_att1,
    const float* __restrict__ v_ws, float* __restrict__ out) {
  __shared__ float tile[4][KNB * PITCH];   // 4 waves x 16.9 KB = 67.6 KB -> 2 blocks/CU
  const int tid = threadIdx.x;
  const int wv = tid >> 6, l = tid & 63, lg = l & 31, hf = l >> 5;
  float* T = &tile[wv][0];

  // A-frags of W1^T: A[m=g=lg][k=d=s*16+hf*8+j] = W1[d, lg]
  f16x8 w1t[8];
#pragma unroll
  for (int s = 0; s < 8; ++s) {
#pragma unroll
    for (int j = 0; j < 8; ++j)
      w1t[s][j] = (_Float16)W_att1[(s * 16 + hf * 8 + j) * HDIM + lg];
  }

  const int nW = gridDim.x * 4;
  for (int n = blockIdx.x * 4 + wv; n < N_NODES; n += nW) {
    const float* nb = neib_feats + (size_t)n * (KNB * DIM);

    // stage: instruction i covers rows 2i+hf fully; lane lg takes 16B chunk lg.
    // Loads first (16 KB in flight per wave), then LDS writes.
    f32x4 stg[16];
#pragma unroll
    for (int i = 0; i < 16; ++i)
      stg[i] = *(const f32x4*)(nb + (2 * i + hf) * DIM + lg * 4);
#pragma unroll
    for (int i = 0; i < 16; ++i)
      *(f32x4*)(T + (2 * i + hf) * PITCH + lg * 4) = stg[i];
    __builtin_amdgcn_s_waitcnt(0);  // drain lgkm before wave-private re-read

    // C = W1^T @ neib^T: B-frag B[k=d][n=neighbor=lg] = tile[lg][d]
    f32x16 acc = zero16();
#pragma unroll
    for (int s = 0; s < 8; ++s) {
      const float* src = T + lg * PITCH + s * 16 + hf * 8;
      f16x8 b;
#pragma unroll
      for (int j = 0; j < 8; ++j) b[j] = (_Float16)src[j];
      acc = __builtin_amdgcn_mfma_f32_32x32x16_f16(w1t[s], b, acc, 0, 0, 0);
    }

    // C[m=g=(r&3)+8*(r>>2)+4*hf][n=k=lg]; score_k = sum_g tanh(C[g,k]) * v[n,g]
    const float* vn = v_ws + n * HDIM;
    float p = 0.f;
#pragma unroll
    for (int r = 0; r < 16; ++r) {
      float t = fast_tanh(acc[r]);
      p = fmaf(t, vn[(r & 3) + 8 * (r >> 2) + 4 * hf], p);
    }
    p += __shfl_xor(p, 32, 64);  // combine the two halves' g-partitions

    // softmax over k (lane lg holds score k=lg, duplicated across halves)
    float mx = p;
#pragma unroll
    for (int off = 16; off; off >>= 1) mx = fmaxf(mx, __shfl_xor(mx, off, 32));
    float e = __expf(p - mx);
    float sum = e;
#pragma unroll
    for (int off = 16; off; off >>= 1) sum += __shfl_xor(sum, off, 32);
    float w = e * __builtin_amdgcn_rcpf(sum);

    // agg[d] = sum_k w[k]*neib[k,d] from LDS; lane covers d=2l,2l+1
    float a0 = 0.f, a1 = 0.f;
#pragma unroll 8
    for (int k = 0; k < KNB; ++k) {
      float wk = __shfl(w, k, 32);
      float2 rv = *(const float2*)(T + k * PITCH + 2 * l);
      a0 = fmaf(wk, rv.x, a0);
      a1 = fmaf(wk, rv.y, a1);
    }
    *(float2*)(out + (size_t)n * 256 + 128 + 2 * l) = make_float2(a0, a1);
  }
}

// Kernel C: out[:,128:256] = relu(agg @ W_neib), agg read in place.
__global__ __launch_bounds__(256) void k_neib(
    const float* __restrict__ W_neib, float* __restrict__ out) {
  const int tid = threadIdx.x;
  const int wv = tid >> 6, l = tid & 63, lg = l & 31, hf = l >> 5;
  const int r0 = blockIdx.x * 128 + wv * 32;
  const int row = r0 + lg;
  const int rowc = row < N_NODES ? row : N_NODES - 1;

  f16x8 af[8];
#pragma unroll
  for (int s = 0; s < 8; ++s) {
    const float* src = out + (size_t)rowc * 256 + 128 + s * 16 + hf * 8;
#pragma unroll
    for (int j = 0; j < 8; ++j) af[s][j] = (_Float16)src[j];
  }

  for (int ct = 0; ct < 4; ++ct) {
    f32x16 acc = zero16();
#pragma unroll
    for (int s = 0; s < 8; ++s) {
      f16x8 b;
#pragma unroll
      for (int j = 0; j < 8; ++j)
        b[j] = (_Float16)W_neib[(s * 16 + hf * 8 + j) * 128 + ct * 32 + lg];
      acc = __builtin_amdgcn_mfma_f32_32x32x16_f16(af[s], b, acc, 0, 0, 0);
    }
#pragma unroll
    for (int r = 0; r < 16; ++r) {
      int orow = r0 + (r & 3) + 8 * (r >> 2) + 4 * hf;
      if (orow < N_NODES) out[(size_t)orow * 256 + 128 + ct * 32 + lg] = fmaxf(acc[r], 0.f);
    }
  }
}

extern "C" void kernel_launch(void* const* d_in, const int* in_sizes, int n_in,
                              void* d_out, int out_size, void* d_ws, size_t ws_size,
                              hipStream_t stream) {
  (void)in_sizes; (void)n_in; (void)ws_size; (void)out_size;
  const float* node_feats = (const float*)d_in[0];
  const float* neib_feats = (const float*)d_in[1];
  const float* W_att1 = (const float*)d_in[4];
  const float* W_att2 = (const float*)d_in[5];
  const float* W_node = (const float*)d_in[6];
  const float* W_neib = (const float*)d_in[7];
  float* out = (float*)d_out;
  float* v_ws = (float*)d_ws;  // N_NODES * 32 floats = 6.4 MB

  const int nblk = (N_NODES + 127) / 128;  // 391
  k_node<<<dim3(nblk), dim3(256), 0, stream>>>(node_feats, W_att1, W_att2, W_node, out, v_ws);
  k_att<<<dim3(512), dim3(256), 0, stream>>>(neib_feats, W_att1, v_ws, out);
  k_neib<<<dim3(nblk), dim3(256), 0, stream>>>(W_neib, out);
}